// Round 19
// baseline (268.088 us; speedup 1.0000x reference)
//
#include <hip/hip_runtime.h>
#include <math.h>

typedef __attribute__((ext_vector_type(4))) float f32x4;
typedef __attribute__((ext_vector_type(8))) int   i32x8;

#define N_ROWS 8192
#define DFULL 768
#define KSC (1.4426950408889634f / 0.05f)
#define NEGSH (-28.853900817779268f)   // -20 * log2(e)
#define LN2 0.6931471805599453f
#define PLB32 ((size_t)N_ROWS * 32)    // bytes per 32B-kblock plane
// Schraudolph fast-exp2 (mean-zero bias)
#define EXPA 8388608.0f
#define FEXPC ((NEGSH + 126.9427f) * 8388608.0f)
#define DIAGC (LN2 / 8388608.0f)

// ---------------- kernel 1: per-row prefix norms + fp8 convert (32B-plane layout) -------
// One row per WAVE: no LDS, no barriers. 4096 blocks x 256 threads (4 rows/block).
__global__ __launch_bounds__(256) void mcl_prep(
    const float* __restrict__ e1, const float* __restrict__ e2,
    char* __restrict__ h1, char* __restrict__ h2,
    float* __restrict__ inv1, float* __restrict__ inv2)
{
  const int w = threadIdx.x >> 6, lane = threadIdx.x & 63;
  const int b = blockIdx.x * 4 + w;              // 0..16383
  const int mat = b >> 13, row = b & (N_ROWS - 1);
  const float* src = (mat ? e2 : e1) + (size_t)row * DFULL;
  char* dst = mat ? h2 : h1;
  float* invo = mat ? inv2 : inv1;

  float p0 = 0.f, p1 = 0.f, p2 = 0.f, p3 = 0.f, p4 = 0.f;
#pragma unroll
  for (int pass = 0; pass < 3; ++pass) {
    const int k = pass * 256 + lane * 4;
    const f32x4 v = *(const f32x4*)(src + k);
    const float s = v[0]*v[0] + v[1]*v[1] + v[2]*v[2] + v[3]*v[3];
    p0 += (k < 64)  ? s : 0.f;
    p1 += (k < 128) ? s : 0.f;
    p2 += (k < 256) ? s : 0.f;
    p3 += (k < 512) ? s : 0.f;
    p4 += s;
    const int lo = __builtin_amdgcn_cvt_pk_fp8_f32(v[0], v[1], 0, false);
    const int pk = __builtin_amdgcn_cvt_pk_fp8_f32(v[2], v[3], lo, true);
    *(int*)(dst + (size_t)(k >> 5) * PLB32 + (size_t)row * 32 + (k & 31)) = pk;
  }
#pragma unroll
  for (int off = 32; off > 0; off >>= 1) {
    p0 += __shfl_down(p0, off, 64);
    p1 += __shfl_down(p1, off, 64);
    p2 += __shfl_down(p2, off, 64);
    p3 += __shfl_down(p3, off, 64);
    p4 += __shfl_down(p4, off, 64);
  }
  if (lane == 0) {
    invo[0 * N_ROWS + row] = 1.f / fmaxf(sqrtf(p0), 1e-8f);
    invo[1 * N_ROWS + row] = 1.f / fmaxf(sqrtf(p1), 1e-8f);
    invo[2 * N_ROWS + row] = 1.f / fmaxf(sqrtf(p2), 1e-8f);
    invo[3 * N_ROWS + row] = 1.f / fmaxf(sqrtf(p3), 1e-8f);
    invo[4 * N_ROWS + row] = 1.f / fmaxf(sqrtf(p4), 1e-8f);
  }
}

// ---------------- kernel 2: MX-fp8 (K=128) GEMM + pipelined checkpoint softmax ----------
// r15 proven body (direct-L2, barrier-free, Schraudolph EPI, (256,2)) with checkpoint
// work rebalanced: REDUCE_STORE of dcp2/dcp3 deferred into chunks 3/5 so every chunk's
// load shadow contains VALU work.
// Swapped operands: acc[n][m] = mfma(bf[n], af[m], .) ->
//   i (softmax row) = wr*64 + m*16 + (lane&15)         [lane-low]
//   j (reduce axis) = wc*64 + n*16 + (lane>>4)*4 + rg  [register + lane-hi]
__global__ __launch_bounds__(256, 2) void mcl_main(
    const char* __restrict__ h1, const char* __restrict__ h2,
    const float* __restrict__ inv1, const float* __restrict__ inv2,
    float* __restrict__ diag, float* __restrict__ partial)
{
  __shared__ float rowsumW[2][5][128];   // [wc][dim][row], each slot written once

  const int tid = threadIdx.x;
  const int lane = tid & 63, wid = tid >> 6;
  const int wr = wid >> 1, wc = wid & 1;
  const int l15 = lane & 15, lh = lane >> 4;
  const int rgd = l15 & 3;

  // XCD-chunked + 8x8-supertile swizzle (bijective: 4096 = 8 * 512)
  const int id = blockIdx.x;
  const int nid = (id & 7) * 512 + (id >> 3);
  const int st = nid >> 6, tt = nid & 63;
  const int bi = ((st >> 3) << 3) + (tt >> 3);
  const int bj = ((st & 7) << 3) + (tt & 7);
  const int rowA0 = bi * 128, rowB0 = bj * 128;
  const bool dgb = (bi == bj) && (wr == wc) && (lh == (l15 >> 2));

  const char* pa = h1 + (size_t)lh * PLB32 + (size_t)(rowA0 + wr * 64 + l15) * 32;
  const char* pb = h2 + (size_t)lh * PLB32 + (size_t)(rowB0 + wc * 64 + l15) * 32;

  f32x4 acc[4][4];  // [n][m]
#pragma unroll
  for (int n = 0; n < 4; ++n)
#pragma unroll
    for (int m = 0; m < 4; ++m) acc[n][m] = (f32x4)0.f;

#define LOADF(CK) do {                                                         \
    _Pragma("unroll")                                                          \
    for (int m = 0; m < 4; ++m) {                                              \
      af[m] = *(const i32x8*)(pa + (CK) * 4 * PLB32 + m * 512);                \
      bf[m] = *(const i32x8*)(pb + (CK) * 4 * PLB32 + m * 512);                \
    } } while (0)

#define MFMACL() do {                                                          \
    __builtin_amdgcn_s_setprio(1);                                             \
    _Pragma("unroll")                                                          \
    for (int n = 0; n < 4; ++n)                                                \
      _Pragma("unroll")                                                        \
      for (int m = 0; m < 4; ++m)                                              \
        acc[n][m] = __builtin_amdgcn_mfma_scale_f32_16x16x128_f8f6f4(          \
            bf[n], af[m], acc[n][m], 0, 0, 0, 0x7F, 0, 0x7F);                  \
    __builtin_amdgcn_s_setprio(0);                                             \
  } while (0)

#define SUMEXP(RP, T, S1M) do {                                                \
    const f32x4 ub = (T) * (S1M) + FEXPC;                                      \
    RP += __int_as_float((int)ub[0]) + __int_as_float((int)ub[1]) +            \
          __int_as_float((int)ub[2]) + __int_as_float((int)ub[3]); } while (0)

#define RS(RP, DCP) do {                                                       \
    _Pragma("unroll")                                                          \
    for (int m = 0; m < 4; ++m) {                                              \
      float v_ = (RP)[m];                                                      \
      v_ += __shfl_xor(v_, 16, 64);                                            \
      v_ += __shfl_xor(v_, 32, 64);                                            \
      if (lh == 0) rowsumW[wc][(DCP)][wr * 64 + m * 16 + l15] = v_;            \
    } } while (0)

// scale loads issued BEFORE fragment loads -> exps need only partial vmcnt
#define EPIPRE(DCP, S1, S2) do {                                               \
    _Pragma("unroll")                                                          \
    for (int m = 0; m < 4; ++m)                                                \
      S1[m] = inv1[(DCP) * N_ROWS + rowA0 + wr * 64 + m * 16 + l15]            \
              * (KSC * EXPA);                                                  \
    _Pragma("unroll")                                                          \
    for (int n = 0; n < 4; ++n)                                                \
      S2[n] = *(const f32x4*)(inv2 + (DCP) * N_ROWS + rowB0 + wc * 64 +        \
                              n * 16 + (lh << 2));                             \
  } while (0)

// exp + diag part only (RS may be deferred)
#define EPIEXP(DCP, S1, S2, RP) do {                                           \
    _Pragma("unroll")                                                          \
    for (int m = 0; m < 4; ++m) (RP)[m] = 0.f;                                 \
    _Pragma("unroll")                                                          \
    for (int n = 0; n < 4; ++n)                                                \
      _Pragma("unroll")                                                        \
      for (int m = 0; m < 4; ++m) {                                            \
        const f32x4 t = acc[n][m] * S2[n];                                     \
        SUMEXP((RP)[m], t, S1[m]);                                             \
      }                                                                        \
    if (dgb) {                                                                 \
      _Pragma("unroll")                                                        \
      for (int m = 0; m < 4; ++m)                                              \
        diag[(DCP) * N_ROWS + rowA0 + wr * 64 + m * 16 + l15] =                \
            acc[m][m][rgd] * S1[m] * S2[m][rgd] * DIAGC;                       \
    } } while (0)

  i32x8 af[4], bf[4];
  float rpd[4];   // deferred rowsum carrier (dcp2 across c3, dcp3 across c5)

  // ---- chunk 0: masked K<64 pass (dcp0), minimal-liveness t ----
  {
    float s1a[4]; f32x4 s2a[4];
    EPIPRE(0, s1a, s2a);
    LOADF(0);
    const int msk = (lh < 2) ? 0x7F : 0x00;   // e8m0: 1.0 for k<64 lanes, flush-to-0 else
    float rp0[4] = {0.f, 0.f, 0.f, 0.f};
#pragma unroll
    for (int n = 0; n < 4; ++n) {
#pragma unroll
      for (int m = 0; m < 4; ++m) {
        const f32x4 t = __builtin_amdgcn_mfma_scale_f32_16x16x128_f8f6f4(
            bf[n], af[m], (f32x4)0.f, 0, 0, 0, msk, 0, msk);
        acc[n][m] = __builtin_amdgcn_mfma_scale_f32_16x16x128_f8f6f4(
            bf[n], af[m], acc[n][m], 0, 0, 0, 0x7F, 0, 0x7F);
        const f32x4 ts = t * s2a[n];
        SUMEXP(rp0[m], ts, s1a[m]);
        if (n == m && dgb)
          diag[0 * N_ROWS + rowA0 + wr * 64 + m * 16 + l15] =
              t[rgd] * s1a[m] * s2a[m][rgd] * DIAGC;
      }
    }
    RS(rp0, 0);
  }

  // ---- chunk 1: dcp1 (K=128) exp+RS in chunk-1 load shadow ----
  {
    float s1b[4]; f32x4 s2b[4];
    EPIPRE(1, s1b, s2b);
    LOADF(1);
    float rp1[4];
    EPIEXP(1, s1b, s2b, rp1);
    RS(rp1, 1);
    MFMACL();
  }
  // ---- chunk 2: dcp2 (K=256) exp in chunk-2 load shadow; RS deferred ----
  {
    float s1c[4]; f32x4 s2c[4];
    EPIPRE(2, s1c, s2c);
    LOADF(2);
    EPIEXP(2, s1c, s2c, rpd);
    MFMACL();
  }
  // ---- chunk 3: deferred RS(dcp2) fills the load shadow ----
  {
    LOADF(3);
    RS(rpd, 2);
    MFMACL();
  }
  // ---- chunk 4: dcp3 (K=512) exp in chunk-4 load shadow; RS deferred ----
  {
    float s1d[4]; f32x4 s2d4[4];
    EPIPRE(3, s1d, s2d4);
    LOADF(4);
    EPIEXP(3, s1d, s2d4, rpd);
    MFMACL();
  }
  // ---- chunk 5: deferred RS(dcp3) in load shadow; final MFMA + dcp4 (K=768) ----
  {
    float s1e[4]; f32x4 s2e[4];
    EPIPRE(4, s1e, s2e);
    LOADF(5);
    RS(rpd, 3);
    MFMACL();
    float rp4[4];
    EPIEXP(4, s1e, s2e, rp4);
    RS(rp4, 4);
  }

#undef EPIEXP
#undef EPIPRE
#undef RS
#undef SUMEXP
#undef MFMACL
#undef LOADF

  __syncthreads();
  // combine wc halves; one atomicAdd per (d, row) into partial[5][8192]
  for (int x = tid; x < 5 * 128; x += 256) {
    const int d = x >> 7, r = x & 127;
    atomicAdd(&partial[d * N_ROWS + rowA0 + r], rowsumW[0][d][r] + rowsumW[1][d][r]);
  }
}

// ---------------- kernel 3: final reduction ----------------
__global__ __launch_bounds__(256) void mcl_reduce(
    const float* __restrict__ partial, const float* __restrict__ diag,
    float* __restrict__ out)
{
  const int item = blockIdx.x * 256 + threadIdx.x;  // 0..40959
  const int d = item >> 13;
  const int i = item & (N_ROWS - 1);
  const float s = partial[d * N_ROWS + i];
  float term = (20.0f + logf(s) - diag[d * N_ROWS + i]) * (1.0f / 8192.0f);
#pragma unroll
  for (int off = 32; off > 0; off >>= 1) term += __shfl_down(term, off, 64);
  __shared__ float red[4];
  const int lane = threadIdx.x & 63, w = threadIdx.x >> 6;
  if (lane == 0) red[w] = term;
  __syncthreads();
  if (threadIdx.x == 0) atomicAdd(out, red[0] + red[1] + red[2] + red[3]);
}

// ---------------- launcher ----------------
extern "C" void kernel_launch(void* const* d_in, const int* in_sizes, int n_in,
                              void* d_out, int out_size, void* d_ws, size_t ws_size,
                              hipStream_t stream) {
  const float* e1 = (const float*)d_in[0];
  const float* e2 = (const float*)d_in[1];
  char* ws = (char*)d_ws;

  const size_t HBYTES = (size_t)N_ROWS * DFULL;                 // 6,291,456 (fp8)
  const size_t IBYTES = (size_t)5 * N_ROWS * sizeof(float);     //   163,840
  char*  h1      = ws;
  char*  h2      = ws + HBYTES;
  float* inv1    = (float*)(ws + 2 * HBYTES);
  float* inv2    = (float*)(ws + 2 * HBYTES + IBYTES);
  float* diag    = (float*)(ws + 2 * HBYTES + 2 * IBYTES);
  float* partial = (float*)(ws + 2 * HBYTES + 3 * IBYTES);      // 5*8192 floats
  const size_t NEED = 2 * HBYTES + 4 * IBYTES;
  if (ws_size < NEED) return;

  hipMemsetAsync(d_out, 0, sizeof(float) * out_size, stream);
  hipMemsetAsync(partial, 0, IBYTES, stream);
  mcl_prep<<<4096, 256, 0, stream>>>(e1, e2, h1, h2, inv1, inv2);
  mcl_main<<<4096, 256, 0, stream>>>(h1, h2, inv1, inv2, diag, partial);
  mcl_reduce<<<160, 256, 0, stream>>>(partial, diag, (float*)d_out);
}

// Round 20
// 112.940 us; speedup vs baseline: 2.3737x; 2.3737x over previous
//
#include <hip/hip_runtime.h>
#include <math.h>

typedef __attribute__((ext_vector_type(4))) float f32x4;
typedef __attribute__((ext_vector_type(8))) int   i32x8;

#define N_ROWS 8192
#define DFULL 768
#define KSC (1.4426950408889634f / 0.05f)
#define NEGSH (-28.853900817779268f)   // -20 * log2(e)
#define LN2 0.6931471805599453f
#define PLB32 ((size_t)N_ROWS * 32)    // bytes per 32B-kblock plane
// Schraudolph fast-exp2 (mean-zero bias)
#define EXPA 8388608.0f
#define FEXPC ((NEGSH + 126.9427f) * 8388608.0f)
#define DIAGC (LN2 / 8388608.0f)

// ---------------- kernel 1: per-row prefix norms + fp8 convert (32B-plane layout) -------
// One row per WAVE: no LDS, no barriers. 4096 blocks x 256 threads (4 rows/block).
__global__ __launch_bounds__(256) void mcl_prep(
    const float* __restrict__ e1, const float* __restrict__ e2,
    char* __restrict__ h1, char* __restrict__ h2,
    float* __restrict__ inv1, float* __restrict__ inv2)
{
  const int w = threadIdx.x >> 6, lane = threadIdx.x & 63;
  const int b = blockIdx.x * 4 + w;              // 0..16383
  const int mat = b >> 13, row = b & (N_ROWS - 1);
  const float* src = (mat ? e2 : e1) + (size_t)row * DFULL;
  char* dst = mat ? h2 : h1;
  float* invo = mat ? inv2 : inv1;

  float p0 = 0.f, p1 = 0.f, p2 = 0.f, p3 = 0.f, p4 = 0.f;
#pragma unroll
  for (int pass = 0; pass < 3; ++pass) {
    const int k = pass * 256 + lane * 4;
    const f32x4 v = *(const f32x4*)(src + k);
    const float s = v[0]*v[0] + v[1]*v[1] + v[2]*v[2] + v[3]*v[3];
    p0 += (k < 64)  ? s : 0.f;
    p1 += (k < 128) ? s : 0.f;
    p2 += (k < 256) ? s : 0.f;
    p3 += (k < 512) ? s : 0.f;
    p4 += s;
    const int lo = __builtin_amdgcn_cvt_pk_fp8_f32(v[0], v[1], 0, false);
    const int pk = __builtin_amdgcn_cvt_pk_fp8_f32(v[2], v[3], lo, true);
    *(int*)(dst + (size_t)(k >> 5) * PLB32 + (size_t)row * 32 + (k & 31)) = pk;
  }
#pragma unroll
  for (int off = 32; off > 0; off >>= 1) {
    p0 += __shfl_down(p0, off, 64);
    p1 += __shfl_down(p1, off, 64);
    p2 += __shfl_down(p2, off, 64);
    p3 += __shfl_down(p3, off, 64);
    p4 += __shfl_down(p4, off, 64);
  }
  if (lane == 0) {
    invo[0 * N_ROWS + row] = 1.f / fmaxf(sqrtf(p0), 1e-8f);
    invo[1 * N_ROWS + row] = 1.f / fmaxf(sqrtf(p1), 1e-8f);
    invo[2 * N_ROWS + row] = 1.f / fmaxf(sqrtf(p2), 1e-8f);
    invo[3 * N_ROWS + row] = 1.f / fmaxf(sqrtf(p3), 1e-8f);
    invo[4 * N_ROWS + row] = 1.f / fmaxf(sqrtf(p4), 1e-8f);
  }
}

// ---------------- kernel 2: MX-fp8 (K=128) GEMM + pipelined checkpoint softmax ----------
// EXACT r15 proven body (100.6 us, VGPR 128, no spill): direct-L2 fragment loads,
// barrier-free main loop, Schraudolph fast-exp2, scale pre-loads before fragment loads,
// (256,2) envelope. Swapped operands: acc[n][m] = mfma(bf[n], af[m], .) ->
//   i (softmax row) = wr*64 + m*16 + (lane&15)         [lane-low]
//   j (reduce axis) = wc*64 + n*16 + (lane>>4)*4 + rg  [register + lane-hi]
__global__ __launch_bounds__(256, 2) void mcl_main(
    const char* __restrict__ h1, const char* __restrict__ h2,
    const float* __restrict__ inv1, const float* __restrict__ inv2,
    float* __restrict__ diag, float* __restrict__ partial)
{
  __shared__ float rowsumW[2][5][128];   // [wc][dim][row], each slot written once

  const int tid = threadIdx.x;
  const int lane = tid & 63, wid = tid >> 6;
  const int wr = wid >> 1, wc = wid & 1;
  const int l15 = lane & 15, lh = lane >> 4;
  const int rgd = l15 & 3;

  // XCD-chunked + 8x8-supertile swizzle (bijective: 4096 = 8 * 512)
  const int id = blockIdx.x;
  const int nid = (id & 7) * 512 + (id >> 3);
  const int st = nid >> 6, tt = nid & 63;
  const int bi = ((st >> 3) << 3) + (tt >> 3);
  const int bj = ((st & 7) << 3) + (tt & 7);
  const int rowA0 = bi * 128, rowB0 = bj * 128;
  const bool dgb = (bi == bj) && (wr == wc) && (lh == (l15 >> 2));

  const char* pa = h1 + (size_t)lh * PLB32 + (size_t)(rowA0 + wr * 64 + l15) * 32;
  const char* pb = h2 + (size_t)lh * PLB32 + (size_t)(rowB0 + wc * 64 + l15) * 32;

  f32x4 acc[4][4];  // [n][m]
#pragma unroll
  for (int n = 0; n < 4; ++n)
#pragma unroll
    for (int m = 0; m < 4; ++m) acc[n][m] = (f32x4)0.f;

#define LOADF(CK) do {                                                         \
    _Pragma("unroll")                                                          \
    for (int m = 0; m < 4; ++m) {                                              \
      af[m] = *(const i32x8*)(pa + (CK) * 4 * PLB32 + m * 512);                \
      bf[m] = *(const i32x8*)(pb + (CK) * 4 * PLB32 + m * 512);                \
    } } while (0)

#define MFMACL() do {                                                          \
    __builtin_amdgcn_s_setprio(1);                                             \
    _Pragma("unroll")                                                          \
    for (int n = 0; n < 4; ++n)                                                \
      _Pragma("unroll")                                                        \
      for (int m = 0; m < 4; ++m)                                              \
        acc[n][m] = __builtin_amdgcn_mfma_scale_f32_16x16x128_f8f6f4(          \
            bf[n], af[m], acc[n][m], 0, 0, 0, 0x7F, 0, 0x7F);                  \
    __builtin_amdgcn_s_setprio(0);                                             \
  } while (0)

#define SUMEXP(RP, T, S1M) do {                                                \
    const f32x4 ub = (T) * (S1M) + FEXPC;                                      \
    RP += __int_as_float((int)ub[0]) + __int_as_float((int)ub[1]) +            \
          __int_as_float((int)ub[2]) + __int_as_float((int)ub[3]); } while (0)

#define REDUCE_STORE(RP, DCP) do {                                             \
    _Pragma("unroll")                                                          \
    for (int m = 0; m < 4; ++m) {                                              \
      float v_ = (RP)[m];                                                      \
      v_ += __shfl_xor(v_, 16, 64);                                            \
      v_ += __shfl_xor(v_, 32, 64);                                            \
      if (lh == 0) rowsumW[wc][(DCP)][wr * 64 + m * 16 + l15] = v_;            \
    } } while (0)

// scale pre-load (issue BEFORE fragment loads so exps need only partial vmcnt)
#define EPIPRE(DCP, S1, S2) do {                                               \
    _Pragma("unroll")                                                          \
    for (int m = 0; m < 4; ++m)                                                \
      S1[m] = inv1[(DCP) * N_ROWS + rowA0 + wr * 64 + m * 16 + l15]            \
              * (KSC * EXPA);                                                  \
    _Pragma("unroll")                                                          \
    for (int n = 0; n < 4; ++n)                                                \
      S2[n] = *(const f32x4*)(inv2 + (DCP) * N_ROWS + rowB0 + wc * 64 +        \
                              n * 16 + (lh << 2));                             \
  } while (0)

// exp + reduce + diag from current acc (scales already resident)
#define EPIMAIN(DCP, S1, S2) do {                                              \
    float rp[4] = {0.f, 0.f, 0.f, 0.f};                                        \
    _Pragma("unroll")                                                          \
    for (int n = 0; n < 4; ++n)                                                \
      _Pragma("unroll")                                                        \
      for (int m = 0; m < 4; ++m) {                                            \
        const f32x4 t = acc[n][m] * S2[n];                                     \
        SUMEXP(rp[m], t, S1[m]);                                               \
      }                                                                        \
    REDUCE_STORE(rp, (DCP));                                                   \
    if (dgb) {                                                                 \
      _Pragma("unroll")                                                        \
      for (int m = 0; m < 4; ++m)                                              \
        diag[(DCP) * N_ROWS + rowA0 + wr * 64 + m * 16 + l15] =                \
            acc[m][m][rgd] * S1[m] * S2[m][rgd] * DIAGC;                       \
    } } while (0)

  i32x8 af[4], bf[4];

  // ---------------- chunk 0: masked K<64 pass (dcp0), minimal-liveness t --------------
  {
    float s1a[4]; f32x4 s2a[4];
    EPIPRE(0, s1a, s2a);
    LOADF(0);
    const int msk = (lh < 2) ? 0x7F : 0x00;   // e8m0: 1.0 for k<64 lanes, flush-to-0 else
    float rp0[4] = {0.f, 0.f, 0.f, 0.f};
#pragma unroll
    for (int n = 0; n < 4; ++n) {
#pragma unroll
      for (int m = 0; m < 4; ++m) {
        const f32x4 t = __builtin_amdgcn_mfma_scale_f32_16x16x128_f8f6f4(
            bf[n], af[m], (f32x4)0.f, 0, 0, 0, msk, 0, msk);
        acc[n][m] = __builtin_amdgcn_mfma_scale_f32_16x16x128_f8f6f4(
            bf[n], af[m], acc[n][m], 0, 0, 0, 0x7F, 0, 0x7F);
        const f32x4 ts = t * s2a[n];
        SUMEXP(rp0[m], ts, s1a[m]);
        if (n == m && dgb)
          diag[0 * N_ROWS + rowA0 + wr * 64 + m * 16 + l15] =
              t[rgd] * s1a[m] * s2a[m][rgd] * DIAGC;
      }
    }
    REDUCE_STORE(rp0, 0);
  }

  // ---------------- chunk 1: dcp1 (K=128) exps in chunk-1 load shadow -----------------
  {
    float s1b[4]; f32x4 s2b[4];
    EPIPRE(1, s1b, s2b);
    LOADF(1);
    EPIMAIN(1, s1b, s2b);
    MFMACL();
  }
  // ---------------- chunk 2: dcp2 (K=256) exps in chunk-2 load shadow -----------------
  {
    float s1c[4]; f32x4 s2c[4];
    EPIPRE(2, s1c, s2c);
    LOADF(2);
    EPIMAIN(2, s1c, s2c);
    MFMACL();
  }
  // ---------------- chunk 3 (no checkpoint) -------------------------------------------
  {
    LOADF(3);
    MFMACL();
  }
  // ---------------- chunk 4: dcp3 (K=512) exps in chunk-4 load shadow -----------------
  {
    float s1d[4]; f32x4 s2d4[4];
    EPIPRE(3, s1d, s2d4);
    LOADF(4);
    EPIMAIN(3, s1d, s2d4);
    MFMACL();
  }
  // ---------------- chunk 5 + final checkpoint dcp4 (K=768) ---------------------------
  {
    float s1e[4]; f32x4 s2e[4];
    EPIPRE(4, s1e, s2e);
    LOADF(5);
    MFMACL();
    EPIMAIN(4, s1e, s2e);
  }

#undef EPIMAIN
#undef EPIPRE
#undef REDUCE_STORE
#undef SUMEXP
#undef MFMACL
#undef LOADF

  __syncthreads();
  // combine wc halves; one atomicAdd per (d, row) into partial[5][8192]
  for (int x = tid; x < 5 * 128; x += 256) {
    const int d = x >> 7, r = x & 127;
    atomicAdd(&partial[d * N_ROWS + rowA0 + r], rowsumW[0][d][r] + rowsumW[1][d][r]);
  }
}

// ---------------- kernel 3: final reduction ----------------
__global__ __launch_bounds__(256) void mcl_reduce(
    const float* __restrict__ partial, const float* __restrict__ diag,
    float* __restrict__ out)
{
  const int item = blockIdx.x * 256 + threadIdx.x;  // 0..40959
  const int d = item >> 13;
  const int i = item & (N_ROWS - 1);
  const float s = partial[d * N_ROWS + i];
  float term = (20.0f + logf(s) - diag[d * N_ROWS + i]) * (1.0f / 8192.0f);
#pragma unroll
  for (int off = 32; off > 0; off >>= 1) term += __shfl_down(term, off, 64);
  __shared__ float red[4];
  const int lane = threadIdx.x & 63, w = threadIdx.x >> 6;
  if (lane == 0) red[w] = term;
  __syncthreads();
  if (threadIdx.x == 0) atomicAdd(out, red[0] + red[1] + red[2] + red[3]);
}

// ---------------- launcher ----------------
extern "C" void kernel_launch(void* const* d_in, const int* in_sizes, int n_in,
                              void* d_out, int out_size, void* d_ws, size_t ws_size,
                              hipStream_t stream) {
  const float* e1 = (const float*)d_in[0];
  const float* e2 = (const float*)d_in[1];
  char* ws = (char*)d_ws;

  const size_t HBYTES = (size_t)N_ROWS * DFULL;                 // 6,291,456 (fp8)
  const size_t IBYTES = (size_t)5 * N_ROWS * sizeof(float);     //   163,840
  char*  h1      = ws;
  char*  h2      = ws + HBYTES;
  float* inv1    = (float*)(ws + 2 * HBYTES);
  float* inv2    = (float*)(ws + 2 * HBYTES + IBYTES);
  float* diag    = (float*)(ws + 2 * HBYTES + 2 * IBYTES);
  float* partial = (float*)(ws + 2 * HBYTES + 3 * IBYTES);      // 5*8192 floats
  const size_t NEED = 2 * HBYTES + 4 * IBYTES;
  if (ws_size < NEED) return;

  hipMemsetAsync(d_out, 0, sizeof(float) * out_size, stream);
  hipMemsetAsync(partial, 0, IBYTES, stream);
  mcl_prep<<<4096, 256, 0, stream>>>(e1, e2, h1, h2, inv1, inv2);
  mcl_main<<<4096, 256, 0, stream>>>(h1, h2, inv1, inv2, diag, partial);
  mcl_reduce<<<160, 256, 0, stream>>>(partial, diag, (float*)d_out);
}